// Round 6
// baseline (231.840 us; speedup 1.0000x reference)
//
#include <hip/hip_runtime.h>

#define N_NODES 65536
#define N_EDGES 1048576
#define B_GRAPHS 32
#define NPG     2048
#define EPS_GN  1e-5f
#define SLOPE   0.01f
#define NBUCKET 256    // coarse buckets (dst>>8), 256 nodes each
#define STCAP   5120   // refine LDS staging capacity (mean 4096 + >10 sigma)

// ---------------- coarse dst-bucket histogram (LDS-privatized) ----------------
__global__ __launch_bounds__(256) void coarse_hist(const int4* __restrict__ dst4,
                                                   int* __restrict__ coarse) {
    __shared__ int lh[256];
    int tid = threadIdx.x;
    lh[tid] = 0;
    __syncthreads();
#pragma unroll
    for (int k = 0; k < 16; ++k) {
        int4 v = dst4[blockIdx.x * 4096 + k * 256 + tid];
        atomicAdd(&lh[v.x >> 8], 1);
        atomicAdd(&lh[v.y >> 8], 1);
        atomicAdd(&lh[v.z >> 8], 1);
        atomicAdd(&lh[v.w >> 8], 1);
    }
    __syncthreads();
    atomicAdd(&coarse[tid], lh[tid]);
}

// ---------------- src histogram: single pass, byte-packed LDS bins ----------------
__global__ __launch_bounds__(256) void src_hist(const int4* __restrict__ src4,
                                                unsigned int* __restrict__ partial) {
    __shared__ unsigned int bins[16384];   // 64 KB
    int tid = threadIdx.x, c = blockIdx.x;
#pragma unroll
    for (int k = 0; k < 64; ++k) bins[k * 256 + tid] = 0u;
    __syncthreads();
#pragma unroll
    for (int k = 0; k < 16; ++k) {
        int4 v = src4[c * 4096 + k * 256 + tid];
        atomicAdd(&bins[v.x >> 2], 1u << ((v.x & 3) * 8));
        atomicAdd(&bins[v.y >> 2], 1u << ((v.y & 3) * 8));
        atomicAdd(&bins[v.z >> 2], 1u << ((v.z & 3) * 8));
        atomicAdd(&bins[v.w >> 2], 1u << ((v.w & 3) * 8));
    }
    __syncthreads();
    unsigned int* dstp = partial + c * 16384;
#pragma unroll
    for (int k = 0; k < 64; ++k) dstp[k * 256 + tid] = bins[k * 256 + tid];
}

// sum byte-counters across 64 chunks -> inv_so (float4 store, 4 nodes/thread)
__global__ __launch_bounds__(256) void reduce_src(const unsigned int* __restrict__ partial,
                                                  float4* __restrict__ inv_so4) {
    int w = blockIdx.x * 256 + threadIdx.x;   // word idx, grid 64
    unsigned int s0 = 0, s1 = 0, s2 = 0, s3 = 0;
#pragma unroll
    for (int c = 0; c < 64; ++c) {
        unsigned int v = partial[c * 16384 + w];
        s0 += v & 255u; s1 += (v >> 8) & 255u; s2 += (v >> 16) & 255u; s3 += v >> 24;
    }
    float4 r;
    r.x = rsqrtf((float)max((int)s0, 1));
    r.y = rsqrtf((float)max((int)s1, 1));
    r.z = rsqrtf((float)max((int)s2, 1));
    r.w = rsqrtf((float)max((int)s3, 1));
    inv_so4[w] = r;
}

// ---------------- scan coarse totals -> bucketBase + cursor init ----------------
__global__ __launch_bounds__(256) void scan_coarse(const int* __restrict__ coarse,
                                                   int* __restrict__ bucketBase,
                                                   int* __restrict__ cursor) {
    __shared__ int s[256];
    int tid = threadIdx.x;
    int my = coarse[tid];
    s[tid] = my;
    __syncthreads();
    for (int off = 1; off < 256; off <<= 1) {
        int t = (tid >= off) ? s[tid - off] : 0;
        __syncthreads();
        s[tid] += t;
        __syncthreads();
    }
    int excl = s[tid] - my;
    bucketBase[tid] = excl;
    cursor[tid] = excl;
    if (tid == 255) bucketBase[256] = s[255];
}

// ---------------- bucket scatter: LDS counting-sort per 4096-edge chunk ----------------
__global__ __launch_bounds__(256) void bucket_scatter(const int4* __restrict__ src4,
                                                      const int4* __restrict__ dst4,
                                                      const float4* __restrict__ ew4,
                                                      int* __restrict__ cursor,
                                                      int2* __restrict__ bedges) {
    __shared__ int lhist[NBUCKET];
    __shared__ int lstart[NBUCKET];
    __shared__ int gbase[NBUCKET];
    __shared__ int sc[NBUCKET];
    __shared__ int2 staged[4096];   // 32 KB
    int tid = threadIdx.x;
    int vbase = blockIdx.x * 1024;  // int4 index base (4096 edges)
    lhist[tid] = 0;
    __syncthreads();
    int w0[16]; int wbr[16]; float wwt[16];
#pragma unroll
    for (int k = 0; k < 4; ++k) {
        int4 s = src4[vbase + k * 256 + tid];
        int4 d = dst4[vbase + k * 256 + tid];
        float4 w = ew4[vbase + k * 256 + tid];
        int ss[4] = {s.x, s.y, s.z, s.w};
        int dd[4] = {d.x, d.y, d.z, d.w};
        float wf[4] = {w.x, w.y, w.z, w.w};
#pragma unroll
        for (int j = 0; j < 4; ++j) {
            int b = dd[j] >> 8;
            w0[k * 4 + j] = ss[j] | ((dd[j] & 255) << 16);
            wwt[k * 4 + j] = wf[j];
            int r = atomicAdd(&lhist[b], 1);
            wbr[k * 4 + j] = (b << 16) | r;
        }
    }
    __syncthreads();
    int cnt = lhist[tid];
    sc[tid] = cnt;
    __syncthreads();
    for (int off = 1; off < 256; off <<= 1) {
        int t = (tid >= off) ? sc[tid - off] : 0;
        __syncthreads();
        sc[tid] += t;
        __syncthreads();
    }
    lstart[tid] = sc[tid] - cnt;
    gbase[tid] = cnt ? atomicAdd(&cursor[tid], cnt) : 0;
    __syncthreads();
#pragma unroll
    for (int k = 0; k < 16; ++k)
        staged[lstart[wbr[k] >> 16] + (wbr[k] & 0xFFFF)] =
            make_int2(w0[k], __float_as_int(wwt[k]));
    __syncthreads();
    int gb = gbase[tid], ls = lstart[tid];
    for (int i = 0; i < cnt; ++i)
        bedges[gb + i] = staged[ls + i];
}

// ---------------- refine: bucket-sorted -> per-node CSR sorted by src-octant ----------------
// key = (dl<<4) | (src>>12): per-node edge lists ordered into 16 src-octants so all
// co-resident agg blocks sweep the same ~1MB src window (L2-resident gathers).
// thread t owns node t's 16 bins -> rowp/inv_si fall out of the per-thread sums.
__global__ __launch_bounds__(256) void refine_kernel(const int2* __restrict__ bedges,
                                                     const int* __restrict__ bucketBase,
                                                     int* __restrict__ rowp,
                                                     float* __restrict__ inv_si,
                                                     int2* __restrict__ csr) {
    __shared__ int hist[4096];      // 16 KB; later reused as cursors
    __shared__ int sc[256];
    __shared__ int2 staged[STCAP];  // 40 KB
    int tid = threadIdx.x, b = blockIdx.x;
    int e0 = bucketBase[b], e1 = bucketBase[b + 1];
    int nE = e1 - e0;
#pragma unroll
    for (int k = 0; k < 16; ++k) hist[k * 256 + tid] = 0;
    __syncthreads();
    for (int i = tid; i < nE; i += 256) {
        int2 e = bedges[e0 + i];
        if (i < STCAP) staged[i] = e;
        int key = (((e.x >> 16) & 255) << 4) | ((e.x & 0xFFFF) >> 12);
        atomicAdd(&hist[key], 1);
    }
    __syncthreads();
    // per-thread (= per-node) exclusive scan of 16 bins, then block scan
    int loc[16];
    int run = 0;
    int base = tid << 4;
#pragma unroll
    for (int j = 0; j < 16; ++j) { loc[j] = run; run += hist[base + j]; }
    sc[tid] = run;
    __syncthreads();
    for (int off = 1; off < 256; off <<= 1) {
        int t = (tid >= off) ? sc[tid - off] : 0;
        __syncthreads();
        sc[tid] += t;
        __syncthreads();
    }
    int start = sc[tid] - run;      // node's exclusive start within bucket
    rowp[b * 256 + tid] = e0 + start;
    inv_si[b * 256 + tid] = rsqrtf((float)max(run, 1));
    if (b == 255 && tid == 255) rowp[65536] = N_EDGES;
#pragma unroll
    for (int j = 0; j < 16; ++j) hist[base + j] = start + loc[j];   // own bins only
    __syncthreads();
    for (int i = tid; i < nE; i += 256) {
        int2 e = (i < STCAP) ? staged[i] : bedges[e0 + i];
        int key = (((e.x >> 16) & 255) << 4) | ((e.x & 0xFFFF) >> 12);
        int pos = atomicAdd(&hist[key], 1);
        csr[e0 + pos] = make_int2(e.x & 0xFFFF, e.y);
    }
}

// ---------------- dense: out[r][c] = sum_k f(in[r][k]) * W[k][c] ----------------
__global__ __launch_bounds__(256) void gemm_kernel(const float* __restrict__ in,
                                                   const float* __restrict__ W,
                                                   const float* __restrict__ inv_so,
                                                   const float* __restrict__ alpha,
                                                   const float* __restrict__ beta,
                                                   float* __restrict__ out) {
    __shared__ float wT[64][68];
    __shared__ float xlds[16][64];
    int tid = threadIdx.x;
#pragma unroll
    for (int j = 0; j < 16; ++j) {
        int i = j * 256 + tid;
        wT[i & 63][i >> 6] = W[i];
    }
    int r0 = blockIdx.x * 16;
#pragma unroll
    for (int j = 0; j < 4; ++j) {
        int i = j * 256 + tid;
        int r = i >> 6, k = i & 63;
        int gr = r0 + r;
        float v = in[(size_t)gr * 64 + k];
        if (alpha) v = alpha[k] * v + beta[k];
        xlds[r][k] = v * inv_so[gr];
    }
    __syncthreads();
    int c = tid & 63;
    int rg = tid >> 6;
    float acc[4] = {0.f, 0.f, 0.f, 0.f};
#pragma unroll
    for (int k0 = 0; k0 < 64; k0 += 4) {
        float4 wv = *(const float4*)&wT[c][k0];
#pragma unroll
        for (int j = 0; j < 4; ++j) {
            float4 xv = *(const float4*)&xlds[rg * 4 + j][k0];
            acc[j] += xv.x * wv.x + xv.y * wv.y + xv.z * wv.z + xv.w * wv.w;
        }
    }
#pragma unroll
    for (int j = 0; j < 4; ++j)
        out[(size_t)(r0 + rg * 4 + j) * 64 + c] = acc[j];
}

// ---------------- pull-aggregation + inv_si + LeakyReLU + fused stats/pool ----------------
__global__ __launch_bounds__(256) void agg_kernel(const float4* __restrict__ T4,
                                                  const int* __restrict__ rowp,
                                                  const float* __restrict__ inv_si,
                                                  const int2* __restrict__ csr,
                                                  float4* __restrict__ Y4,
                                                  float4* __restrict__ statsP4,
                                                  float* __restrict__ pooledSum) {
    __shared__ float4 ls[256];
    __shared__ float4 lq[256];
    int tid = threadIdx.x;
    int node = blockIdx.x * 16 + (tid >> 4);
    int l16 = tid & 15;
    int start = rowp[node];
    int cnt = rowp[node + 1] - start;
    const int2* ep = csr + start;
    float4 acc = make_float4(0.f, 0.f, 0.f, 0.f);
    int i = 0;
    for (; i + 8 <= cnt; i += 8) {
        int2 e[8];
#pragma unroll
        for (int k = 0; k < 8; ++k) e[k] = ep[i + k];
        float4 a[8];
#pragma unroll
        for (int k = 0; k < 8; ++k) a[k] = T4[(size_t)e[k].x * 16 + l16];
#pragma unroll
        for (int k = 0; k < 8; ++k) {
            float w = __int_as_float(e[k].y);
            acc.x += a[k].x * w;
            acc.y += a[k].y * w;
            acc.z += a[k].z * w;
            acc.w += a[k].w * w;
        }
    }
    for (; i + 2 <= cnt; i += 2) {
        int2 e0 = ep[i], e1 = ep[i + 1];
        float4 a0 = T4[(size_t)e0.x * 16 + l16];
        float4 a1 = T4[(size_t)e1.x * 16 + l16];
        float w0 = __int_as_float(e0.y), w1 = __int_as_float(e1.y);
        acc.x += a0.x * w0 + a1.x * w1;
        acc.y += a0.y * w0 + a1.y * w1;
        acc.z += a0.z * w0 + a1.z * w1;
        acc.w += a0.w * w0 + a1.w * w1;
    }
    if (i < cnt) {
        int2 e = ep[i];
        float4 a = T4[(size_t)e.x * 16 + l16];
        float w = __int_as_float(e.y);
        acc.x += a.x * w; acc.y += a.y * w; acc.z += a.z * w; acc.w += a.w * w;
    }
    float s = inv_si[node];
    float4 v;
    v.x = acc.x * s; v.x = (v.x >= 0.f) ? v.x : SLOPE * v.x;
    v.y = acc.y * s; v.y = (v.y >= 0.f) ? v.y : SLOPE * v.y;
    v.z = acc.z * s; v.z = (v.z >= 0.f) ? v.z : SLOPE * v.z;
    v.w = acc.w * s; v.w = (v.w >= 0.f) ? v.w : SLOPE * v.w;
    Y4[(size_t)node * 16 + l16] = v;

    // fused stats (and pool) partials
    ls[tid] = v;
    lq[tid] = make_float4(v.x * v.x, v.y * v.y, v.z * v.z, v.w * v.w);
    __syncthreads();
    for (int off = 128; off >= 16; off >>= 1) {
        if (tid < off) {
            float4 a = ls[tid + off], b = lq[tid + off];
            ls[tid].x += a.x; ls[tid].y += a.y; ls[tid].z += a.z; ls[tid].w += a.w;
            lq[tid].x += b.x; lq[tid].y += b.y; lq[tid].z += b.z; lq[tid].w += b.w;
        }
        __syncthreads();
    }
    if (tid < 32)
        statsP4[blockIdx.x * 32 + tid] = (tid < 16) ? ls[tid] : lq[tid - 16];
    if (pooledSum && tid < 16) {
        int graph = blockIdx.x >> 7;   // 128 blocks per graph
        float4 a = ls[tid];
        atomicAdd(&pooledSum[graph * 64 + tid * 4 + 0], a.x);
        atomicAdd(&pooledSum[graph * 64 + tid * 4 + 1], a.y);
        atomicAdd(&pooledSum[graph * 64 + tid * 4 + 2], a.z);
        atomicAdd(&pooledSum[graph * 64 + tid * 4 + 3], a.w);
    }
}

// ---------------- reduce 4096x128 stats partials -> stats[128] ----------------
__global__ __launch_bounds__(256) void reduce_stats(const float* __restrict__ statsP,
                                                    float* __restrict__ stats) {
    __shared__ float red[256];
    int tid = threadIdx.x, b = blockIdx.x;   // grid 64
    int col = tid & 127, half = tid >> 7;
    float s = 0.f;
    for (int i = half; i < 64; i += 2)
        s += statsP[(size_t)(b * 64 + i) * 128 + col];
    red[tid] = s;
    __syncthreads();
    if (tid < 128) atomicAdd(&stats[col], red[tid] + red[tid + 128]);
}

// GraphNorm(y) = alpha*y + beta
__global__ void finalize_kernel(const float* __restrict__ Sy, const float* __restrict__ Syy,
                                const float* __restrict__ w, const float* __restrict__ b,
                                const float* __restrict__ a,
                                float* __restrict__ alpha, float* __restrict__ beta) {
    int f = threadIdx.x;
    if (f < 64) {
        float m = Sy[f] * (1.f / N_NODES);
        float q = Syy[f] * (1.f / N_NODES);
        float af = a[f];
        float var = q - 2.f * af * m * m + af * af * m * m;
        float stdv = sqrtf(var + EPS_GN);
        float al = w[f] / stdv;
        alpha[f] = al;
        beta[f] = b[f] - al * af * m;
    }
}

// ---------------- final: GN2 finalize + affine on pooled mean + @ Wc^T ----------------
__global__ __launch_bounds__(256) void out_kernel(const float* __restrict__ stats2,
                                                  const float* __restrict__ gn_w,
                                                  const float* __restrict__ gn_b,
                                                  const float* __restrict__ gn_a,
                                                  const float* __restrict__ pooledSum,
                                                  const float* __restrict__ Wc,
                                                  float* __restrict__ out) {
    __shared__ float al[64], be[64];
    __shared__ float p[B_GRAPHS * 64];
    int tid = threadIdx.x;
    if (tid < 64) {
        float m = stats2[tid] * (1.f / N_NODES);
        float q = stats2[64 + tid] * (1.f / N_NODES);
        float af = gn_a[tid];
        float var = q - 2.f * af * m * m + af * af * m * m;
        float a_ = gn_w[tid] / sqrtf(var + EPS_GN);
        al[tid] = a_;
        be[tid] = gn_b[tid] - a_ * af * m;
    }
    __syncthreads();
    for (int i = tid; i < B_GRAPHS * 64; i += 256) {
        int f = i & 63;
        p[i] = al[f] * (pooledSum[i] * (1.f / NPG)) + be[f];
    }
    __syncthreads();
    for (int idx = tid; idx < B_GRAPHS * 32; idx += 256) {
        int g = idx >> 5, o = idx & 31;
        float acc = 0.f;
        for (int f = 0; f < 64; ++f)
            acc += p[g * 64 + f] * Wc[o * 64 + f];
        out[idx] = acc;
    }
}

extern "C" void kernel_launch(void* const* d_in, const int* in_sizes, int n_in,
                              void* d_out, int out_size, void* d_ws, size_t ws_size,
                              hipStream_t stream) {
    const float* x     = (const float*)d_in[0];
    const float* ew    = (const float*)d_in[1];
    const float* W1    = (const float*)d_in[2];
    const float* W2    = (const float*)d_in[3];
    const float* Wc    = (const float*)d_in[4];
    const float* gn1_w = (const float*)d_in[5];
    const float* gn1_b = (const float*)d_in[6];
    const float* gn1_a = (const float*)d_in[7];
    const float* gn2_w = (const float*)d_in[8];
    const float* gn2_b = (const float*)d_in[9];
    const float* gn2_a = (const float*)d_in[10];
    const int* src     = (const int*)d_in[11];
    const int* dst     = (const int*)d_in[12];

    char* ws = (char*)d_ws;
    int*   coarse     = (int*)(ws + 0);             // 1 KB   [memset]
    float* stats1     = (float*)(ws + 1024);        // 512 B  [memset]
    float* stats2     = (float*)(ws + 1536);        // 512 B  [memset]
    float* pooledSum  = (float*)(ws + 2048);        // 8 KB   [memset]
    float* ab1        = (float*)(ws + 10240);       // 512 B
    int*   bucketBase = (int*)(ws + 11264);         // 257 ints
    int*   cursor     = (int*)(ws + 12544);         // 1 KB
    int*   rowp       = (int*)(ws + 16384);         // 65537 ints (~256 KB)
    float* inv_so     = (float*)(ws + 294912);      // 256 KB
    float* inv_si     = (float*)(ws + 557056);      // 256 KB
    unsigned int* partial = (unsigned int*)(ws + (1u << 20)); // 4 MB (dead after reduce_src)
    int2*  csr        = (int2*)(ws + (1u << 20));   // 8 MB (overlaps partial)
    int2*  bedges     = (int2*)(ws + (9u << 20));   // 8 MB
    float* bufA       = (float*)(ws + (17u << 20)); // 16 MB
    float* bufB       = (float*)(ws + (33u << 20)); // 16 MB
    float* statsP     = (float*)(ws + (49u << 20)); // 2 MB (4096 x 128)

    hipMemsetAsync(ws, 0, 10240, stream);

    // graph structure (recomputed each call)
    coarse_hist<<<64, 256, 0, stream>>>((const int4*)dst, coarse);
    src_hist<<<64, 256, 0, stream>>>((const int4*)src, partial);
    scan_coarse<<<1, 256, 0, stream>>>(coarse, bucketBase, cursor);
    reduce_src<<<64, 256, 0, stream>>>(partial, (float4*)inv_so);
    bucket_scatter<<<256, 256, 0, stream>>>((const int4*)src, (const int4*)dst,
                                            (const float4*)ew, cursor, bedges);
    refine_kernel<<<NBUCKET, 256, 0, stream>>>(bedges, bucketBase, rowp, inv_si, csr);

    // layer 1
    gemm_kernel<<<N_NODES / 16, 256, 0, stream>>>(x, W1, inv_so, nullptr, nullptr, bufA);
    agg_kernel<<<N_NODES / 16, 256, 0, stream>>>((const float4*)bufA, rowp, inv_si, csr,
                                                 (float4*)bufB, (float4*)statsP, nullptr);
    reduce_stats<<<64, 256, 0, stream>>>(statsP, stats1);
    finalize_kernel<<<1, 64, 0, stream>>>(stats1, stats1 + 64, gn1_w, gn1_b, gn1_a,
                                          ab1 + 0, ab1 + 64);

    // layer 2 (GraphNorm-1 affine fused into GEMM2 load; stats+pool fused into agg)
    gemm_kernel<<<N_NODES / 16, 256, 0, stream>>>(bufB, W2, inv_so, ab1 + 0, ab1 + 64, bufA);
    agg_kernel<<<N_NODES / 16, 256, 0, stream>>>((const float4*)bufA, rowp, inv_si, csr,
                                                 (float4*)bufB, (float4*)statsP, pooledSum);
    reduce_stats<<<64, 256, 0, stream>>>(statsP, stats2);

    // GN2 finalize + pooled affine + classifier (single block)
    out_kernel<<<1, 256, 0, stream>>>(stats2, gn2_w, gn2_b, gn2_a, pooledSum, Wc,
                                      (float*)d_out);
}

// Round 7
// 197.074 us; speedup vs baseline: 1.1764x; 1.1764x over previous
//
#include <hip/hip_runtime.h>

#define N_NODES 65536
#define N_EDGES 1048576
#define B_GRAPHS 32
#define NPG     2048
#define EPS_GN  1e-5f
#define SLOPE   0.01f
#define NBUCKET 256    // coarse buckets (dst>>8), 256 nodes each
#define STCAP   5120   // refine LDS staging capacity (mean 4096 + >10 sigma)

typedef unsigned short ushort_t;
typedef unsigned int uint_t;

// float -> bf16 with round-to-nearest-even (NaN ignored: inputs are finite)
static __device__ __forceinline__ ushort_t f2bf(float f) {
    uint_t u = __float_as_uint(f);
    return (ushort_t)((u + 0x7FFFu + ((u >> 16) & 1u)) >> 16);
}

// ---------------- coarse dst-bucket histogram (LDS-privatized) ----------------
__global__ __launch_bounds__(256) void coarse_hist(const int4* __restrict__ dst4,
                                                   int* __restrict__ coarse) {
    __shared__ int lh[256];
    int tid = threadIdx.x;
    lh[tid] = 0;
    __syncthreads();
#pragma unroll
    for (int k = 0; k < 16; ++k) {
        int4 v = dst4[blockIdx.x * 4096 + k * 256 + tid];
        atomicAdd(&lh[v.x >> 8], 1);
        atomicAdd(&lh[v.y >> 8], 1);
        atomicAdd(&lh[v.z >> 8], 1);
        atomicAdd(&lh[v.w >> 8], 1);
    }
    __syncthreads();
    atomicAdd(&coarse[tid], lh[tid]);
}

// ---------------- src histogram: single pass, byte-packed LDS bins ----------------
__global__ __launch_bounds__(256) void src_hist(const int4* __restrict__ src4,
                                                unsigned int* __restrict__ partial) {
    __shared__ unsigned int bins[16384];   // 64 KB
    int tid = threadIdx.x, c = blockIdx.x;
#pragma unroll
    for (int k = 0; k < 64; ++k) bins[k * 256 + tid] = 0u;
    __syncthreads();
#pragma unroll
    for (int k = 0; k < 16; ++k) {
        int4 v = src4[c * 4096 + k * 256 + tid];
        atomicAdd(&bins[v.x >> 2], 1u << ((v.x & 3) * 8));
        atomicAdd(&bins[v.y >> 2], 1u << ((v.y & 3) * 8));
        atomicAdd(&bins[v.z >> 2], 1u << ((v.z & 3) * 8));
        atomicAdd(&bins[v.w >> 2], 1u << ((v.w & 3) * 8));
    }
    __syncthreads();
    unsigned int* dstp = partial + c * 16384;
#pragma unroll
    for (int k = 0; k < 64; ++k) dstp[k * 256 + tid] = bins[k * 256 + tid];
}

// sum byte-counters across 64 chunks -> inv_so (float4 store, 4 nodes/thread)
__global__ __launch_bounds__(256) void reduce_src(const unsigned int* __restrict__ partial,
                                                  float4* __restrict__ inv_so4) {
    int w = blockIdx.x * 256 + threadIdx.x;   // word idx, grid 64
    unsigned int s0 = 0, s1 = 0, s2 = 0, s3 = 0;
#pragma unroll
    for (int c = 0; c < 64; ++c) {
        unsigned int v = partial[c * 16384 + w];
        s0 += v & 255u; s1 += (v >> 8) & 255u; s2 += (v >> 16) & 255u; s3 += v >> 24;
    }
    float4 r;
    r.x = rsqrtf((float)max((int)s0, 1));
    r.y = rsqrtf((float)max((int)s1, 1));
    r.z = rsqrtf((float)max((int)s2, 1));
    r.w = rsqrtf((float)max((int)s3, 1));
    inv_so4[w] = r;
}

// ---------------- scan coarse totals -> bucketBase + cursor init ----------------
__global__ __launch_bounds__(256) void scan_coarse(const int* __restrict__ coarse,
                                                   int* __restrict__ bucketBase,
                                                   int* __restrict__ cursor) {
    __shared__ int s[256];
    int tid = threadIdx.x;
    int my = coarse[tid];
    s[tid] = my;
    __syncthreads();
    for (int off = 1; off < 256; off <<= 1) {
        int t = (tid >= off) ? s[tid - off] : 0;
        __syncthreads();
        s[tid] += t;
        __syncthreads();
    }
    int excl = s[tid] - my;
    bucketBase[tid] = excl;
    cursor[tid] = excl;
    if (tid == 255) bucketBase[256] = s[255];
}

// ---------------- bucket scatter: LDS counting-sort per 4096-edge chunk ----------------
__global__ __launch_bounds__(256) void bucket_scatter(const int4* __restrict__ src4,
                                                      const int4* __restrict__ dst4,
                                                      const float4* __restrict__ ew4,
                                                      int* __restrict__ cursor,
                                                      int2* __restrict__ bedges) {
    __shared__ int lhist[NBUCKET];
    __shared__ int lstart[NBUCKET];
    __shared__ int gbase[NBUCKET];
    __shared__ int sc[NBUCKET];
    __shared__ int2 staged[4096];   // 32 KB
    int tid = threadIdx.x;
    int vbase = blockIdx.x * 1024;  // int4 index base (4096 edges)
    lhist[tid] = 0;
    __syncthreads();
    int w0[16]; int wbr[16]; float wwt[16];
#pragma unroll
    for (int k = 0; k < 4; ++k) {
        int4 s = src4[vbase + k * 256 + tid];
        int4 d = dst4[vbase + k * 256 + tid];
        float4 w = ew4[vbase + k * 256 + tid];
        int ss[4] = {s.x, s.y, s.z, s.w};
        int dd[4] = {d.x, d.y, d.z, d.w};
        float wf[4] = {w.x, w.y, w.z, w.w};
#pragma unroll
        for (int j = 0; j < 4; ++j) {
            int b = dd[j] >> 8;
            w0[k * 4 + j] = ss[j] | ((dd[j] & 255) << 16);
            wwt[k * 4 + j] = wf[j];
            int r = atomicAdd(&lhist[b], 1);
            wbr[k * 4 + j] = (b << 16) | r;
        }
    }
    __syncthreads();
    int cnt = lhist[tid];
    sc[tid] = cnt;
    __syncthreads();
    for (int off = 1; off < 256; off <<= 1) {
        int t = (tid >= off) ? sc[tid - off] : 0;
        __syncthreads();
        sc[tid] += t;
        __syncthreads();
    }
    lstart[tid] = sc[tid] - cnt;
    gbase[tid] = cnt ? atomicAdd(&cursor[tid], cnt) : 0;
    __syncthreads();
#pragma unroll
    for (int k = 0; k < 16; ++k)
        staged[lstart[wbr[k] >> 16] + (wbr[k] & 0xFFFF)] =
            make_int2(w0[k], __float_as_int(wwt[k]));
    __syncthreads();
    int gb = gbase[tid], ls = lstart[tid];
    for (int i = 0; i < cnt; ++i)
        bedges[gb + i] = staged[ls + i];
}

// ---------------- refine: bucket-sorted -> per-node CSR (src-octant ordered) ----------------
__global__ __launch_bounds__(256) void refine_kernel(const int2* __restrict__ bedges,
                                                     const int* __restrict__ bucketBase,
                                                     int* __restrict__ rowp,
                                                     float* __restrict__ inv_si,
                                                     int2* __restrict__ csr) {
    __shared__ int hist[4096];      // 16 KB; later reused as cursors
    __shared__ int sc[256];
    __shared__ int2 staged[STCAP];  // 40 KB
    int tid = threadIdx.x, b = blockIdx.x;
    int e0 = bucketBase[b], e1 = bucketBase[b + 1];
    int nE = e1 - e0;
#pragma unroll
    for (int k = 0; k < 16; ++k) hist[k * 256 + tid] = 0;
    __syncthreads();
    for (int i = tid; i < nE; i += 256) {
        int2 e = bedges[e0 + i];
        if (i < STCAP) staged[i] = e;
        int key = (((e.x >> 16) & 255) << 4) | ((e.x & 0xFFFF) >> 12);
        atomicAdd(&hist[key], 1);
    }
    __syncthreads();
    int loc[16];
    int run = 0;
    int base = tid << 4;
#pragma unroll
    for (int j = 0; j < 16; ++j) { loc[j] = run; run += hist[base + j]; }
    sc[tid] = run;
    __syncthreads();
    for (int off = 1; off < 256; off <<= 1) {
        int t = (tid >= off) ? sc[tid - off] : 0;
        __syncthreads();
        sc[tid] += t;
        __syncthreads();
    }
    int start = sc[tid] - run;
    rowp[b * 256 + tid] = e0 + start;
    inv_si[b * 256 + tid] = rsqrtf((float)max(run, 1));
    if (b == 255 && tid == 255) rowp[65536] = N_EDGES;
#pragma unroll
    for (int j = 0; j < 16; ++j) hist[base + j] = start + loc[j];
    __syncthreads();
    for (int i = tid; i < nE; i += 256) {
        int2 e = (i < STCAP) ? staged[i] : bedges[e0 + i];
        int key = (((e.x >> 16) & 255) << 4) | ((e.x & 0xFFFF) >> 12);
        int pos = atomicAdd(&hist[key], 1);
        csr[e0 + pos] = make_int2(e.x & 0xFFFF, e.y);
    }
}

// ---------------- dense: T_bf[r][c] = bf16( sum_k f(in[r][k]) * W[k][c] ) ----------------
__global__ __launch_bounds__(256) void gemm_kernel(const float* __restrict__ in,
                                                   const float* __restrict__ W,
                                                   const float* __restrict__ inv_so,
                                                   const float* __restrict__ alpha,
                                                   const float* __restrict__ beta,
                                                   ushort_t* __restrict__ out_bf) {
    __shared__ float wT[64][68];
    __shared__ float xlds[16][64];
    int tid = threadIdx.x;
#pragma unroll
    for (int j = 0; j < 16; ++j) {
        int i = j * 256 + tid;
        wT[i & 63][i >> 6] = W[i];
    }
    int r0 = blockIdx.x * 16;
#pragma unroll
    for (int j = 0; j < 4; ++j) {
        int i = j * 256 + tid;
        int r = i >> 6, k = i & 63;
        int gr = r0 + r;
        float v = in[(size_t)gr * 64 + k];
        if (alpha) v = alpha[k] * v + beta[k];
        xlds[r][k] = v * inv_so[gr];
    }
    __syncthreads();
    int c = tid & 63;
    int rg = tid >> 6;
    float acc[4] = {0.f, 0.f, 0.f, 0.f};
#pragma unroll
    for (int k0 = 0; k0 < 64; k0 += 4) {
        float4 wv = *(const float4*)&wT[c][k0];
#pragma unroll
        for (int j = 0; j < 4; ++j) {
            float4 xv = *(const float4*)&xlds[rg * 4 + j][k0];
            acc[j] += xv.x * wv.x + xv.y * wv.y + xv.z * wv.z + xv.w * wv.w;
        }
    }
#pragma unroll
    for (int j = 0; j < 4; ++j)
        out_bf[(size_t)(r0 + rg * 4 + j) * 64 + c] = f2bf(acc[j]);
}

// ---------------- pull-aggregation (bf16 gather) + inv_si + LeakyReLU + stats/pool ----------
// 8 lanes/node (16B bf16x8 per lane -> one 128B line per edge), 32 nodes/block, unroll 8
__global__ __launch_bounds__(256) void agg_kernel(const ushort_t* __restrict__ Tb,
                                                  const int* __restrict__ rowp,
                                                  const float* __restrict__ inv_si,
                                                  const int2* __restrict__ csr,
                                                  float4* __restrict__ Y4,
                                                  float4* __restrict__ statsP4,
                                                  float* __restrict__ pooledSum) {
    __shared__ float4 s0[256], s1[256], q0[256], q1[256];   // 16 KB
    int tid = threadIdx.x;
    int slot = tid >> 3;             // 0..31
    int node = blockIdx.x * 32 + slot;
    int l8 = tid & 7;
    int start = rowp[node];
    int cnt = rowp[node + 1] - start;
    const int2* ep = csr + start;
    float4 a0 = make_float4(0.f, 0.f, 0.f, 0.f);
    float4 a1 = make_float4(0.f, 0.f, 0.f, 0.f);
    int i = 0;
    for (; i + 8 <= cnt; i += 8) {
        int2 e[8];
#pragma unroll
        for (int k = 0; k < 8; ++k) e[k] = ep[i + k];
        uint4 t[8];
#pragma unroll
        for (int k = 0; k < 8; ++k)
            t[k] = ((const uint4*)(Tb + ((size_t)e[k].x << 6)))[l8];
#pragma unroll
        for (int k = 0; k < 8; ++k) {
            float w = __int_as_float(e[k].y);
            uint4 u = t[k];
            a0.x += __uint_as_float(u.x << 16) * w;
            a0.y += __uint_as_float(u.x & 0xffff0000u) * w;
            a0.z += __uint_as_float(u.y << 16) * w;
            a0.w += __uint_as_float(u.y & 0xffff0000u) * w;
            a1.x += __uint_as_float(u.z << 16) * w;
            a1.y += __uint_as_float(u.z & 0xffff0000u) * w;
            a1.z += __uint_as_float(u.w << 16) * w;
            a1.w += __uint_as_float(u.w & 0xffff0000u) * w;
        }
    }
    for (; i < cnt; ++i) {
        int2 e = ep[i];
        float w = __int_as_float(e.y);
        uint4 u = ((const uint4*)(Tb + ((size_t)e.x << 6)))[l8];
        a0.x += __uint_as_float(u.x << 16) * w;
        a0.y += __uint_as_float(u.x & 0xffff0000u) * w;
        a0.z += __uint_as_float(u.y << 16) * w;
        a0.w += __uint_as_float(u.y & 0xffff0000u) * w;
        a1.x += __uint_as_float(u.z << 16) * w;
        a1.y += __uint_as_float(u.z & 0xffff0000u) * w;
        a1.z += __uint_as_float(u.w << 16) * w;
        a1.w += __uint_as_float(u.w & 0xffff0000u) * w;
    }
    float s = inv_si[node];
    float4 v0, v1;
    v0.x = a0.x * s; v0.x = (v0.x >= 0.f) ? v0.x : SLOPE * v0.x;
    v0.y = a0.y * s; v0.y = (v0.y >= 0.f) ? v0.y : SLOPE * v0.y;
    v0.z = a0.z * s; v0.z = (v0.z >= 0.f) ? v0.z : SLOPE * v0.z;
    v0.w = a0.w * s; v0.w = (v0.w >= 0.f) ? v0.w : SLOPE * v0.w;
    v1.x = a1.x * s; v1.x = (v1.x >= 0.f) ? v1.x : SLOPE * v1.x;
    v1.y = a1.y * s; v1.y = (v1.y >= 0.f) ? v1.y : SLOPE * v1.y;
    v1.z = a1.z * s; v1.z = (v1.z >= 0.f) ? v1.z : SLOPE * v1.z;
    v1.w = a1.w * s; v1.w = (v1.w >= 0.f) ? v1.w : SLOPE * v1.w;
    // Y row: feats l8*8..l8*8+7  -> float4 slots 2*l8, 2*l8+1
    Y4[(size_t)node * 16 + l8 * 2 + 0] = v0;
    Y4[(size_t)node * 16 + l8 * 2 + 1] = v1;

    // fused stats (+pool) partials: reduce over the block's 32 nodes (stride-8 lanes)
    s0[tid] = v0; s1[tid] = v1;
    q0[tid] = make_float4(v0.x * v0.x, v0.y * v0.y, v0.z * v0.z, v0.w * v0.w);
    q1[tid] = make_float4(v1.x * v1.x, v1.y * v1.y, v1.z * v1.z, v1.w * v1.w);
    __syncthreads();
    for (int off = 128; off >= 8; off >>= 1) {
        if (tid < off) {
            float4 a, b;
            a = s0[tid + off]; b = s1[tid + off];
            s0[tid].x += a.x; s0[tid].y += a.y; s0[tid].z += a.z; s0[tid].w += a.w;
            s1[tid].x += b.x; s1[tid].y += b.y; s1[tid].z += b.z; s1[tid].w += b.w;
            a = q0[tid + off]; b = q1[tid + off];
            q0[tid].x += a.x; q0[tid].y += a.y; q0[tid].z += a.z; q0[tid].w += a.w;
            q1[tid].x += b.x; q1[tid].y += b.y; q1[tid].z += b.z; q1[tid].w += b.w;
        }
        __syncthreads();
    }
    if (tid < 8) {
        // statsP row layout: [Sy 16 float4][Syy 16 float4]; lane l8 -> slots 2*l8, 2*l8+1
        float4* row = statsP4 + (size_t)blockIdx.x * 32;
        row[tid * 2 + 0] = s0[tid];
        row[tid * 2 + 1] = s1[tid];
        row[16 + tid * 2 + 0] = q0[tid];
        row[16 + tid * 2 + 1] = q1[tid];
        if (pooledSum) {
            int graph = blockIdx.x >> 6;   // 64 blocks per graph (2048 nodes)
            float* ps = pooledSum + graph * 64 + tid * 8;
            float4 a = s0[tid], b = s1[tid];
            atomicAdd(ps + 0, a.x); atomicAdd(ps + 1, a.y);
            atomicAdd(ps + 2, a.z); atomicAdd(ps + 3, a.w);
            atomicAdd(ps + 4, b.x); atomicAdd(ps + 5, b.y);
            atomicAdd(ps + 6, b.z); atomicAdd(ps + 7, b.w);
        }
    }
}

// ---------------- reduce 2048x128 stats partials -> stats[128] ----------------
__global__ __launch_bounds__(256) void reduce_stats(const float* __restrict__ statsP,
                                                    float* __restrict__ stats) {
    __shared__ float red[256];
    int tid = threadIdx.x, b = blockIdx.x;   // grid 64
    int col = tid & 127, half = tid >> 7;
    float s = 0.f;
    for (int i = half; i < 32; i += 2)
        s += statsP[(size_t)(b * 32 + i) * 128 + col];
    red[tid] = s;
    __syncthreads();
    if (tid < 128) atomicAdd(&stats[col], red[tid] + red[tid + 128]);
}

// GraphNorm(y) = alpha*y + beta
__global__ void finalize_kernel(const float* __restrict__ Sy, const float* __restrict__ Syy,
                                const float* __restrict__ w, const float* __restrict__ b,
                                const float* __restrict__ a,
                                float* __restrict__ alpha, float* __restrict__ beta) {
    int f = threadIdx.x;
    if (f < 64) {
        float m = Sy[f] * (1.f / N_NODES);
        float q = Syy[f] * (1.f / N_NODES);
        float af = a[f];
        float var = q - 2.f * af * m * m + af * af * m * m;
        float stdv = sqrtf(var + EPS_GN);
        float al = w[f] / stdv;
        alpha[f] = al;
        beta[f] = b[f] - al * af * m;
    }
}

// ---------------- final: GN2 finalize + affine on pooled mean + @ Wc^T ----------------
__global__ __launch_bounds__(256) void out_kernel(const float* __restrict__ stats2,
                                                  const float* __restrict__ gn_w,
                                                  const float* __restrict__ gn_b,
                                                  const float* __restrict__ gn_a,
                                                  const float* __restrict__ pooledSum,
                                                  const float* __restrict__ Wc,
                                                  float* __restrict__ out) {
    __shared__ float al[64], be[64];
    __shared__ float p[B_GRAPHS * 64];
    int tid = threadIdx.x;
    if (tid < 64) {
        float m = stats2[tid] * (1.f / N_NODES);
        float q = stats2[64 + tid] * (1.f / N_NODES);
        float af = gn_a[tid];
        float var = q - 2.f * af * m * m + af * af * m * m;
        float a_ = gn_w[tid] / sqrtf(var + EPS_GN);
        al[tid] = a_;
        be[tid] = gn_b[tid] - a_ * af * m;
    }
    __syncthreads();
    for (int i = tid; i < B_GRAPHS * 64; i += 256) {
        int f = i & 63;
        p[i] = al[f] * (pooledSum[i] * (1.f / NPG)) + be[f];
    }
    __syncthreads();
    for (int idx = tid; idx < B_GRAPHS * 32; idx += 256) {
        int g = idx >> 5, o = idx & 31;
        float acc = 0.f;
        for (int f = 0; f < 64; ++f)
            acc += p[g * 64 + f] * Wc[o * 64 + f];
        out[idx] = acc;
    }
}

extern "C" void kernel_launch(void* const* d_in, const int* in_sizes, int n_in,
                              void* d_out, int out_size, void* d_ws, size_t ws_size,
                              hipStream_t stream) {
    const float* x     = (const float*)d_in[0];
    const float* ew    = (const float*)d_in[1];
    const float* W1    = (const float*)d_in[2];
    const float* W2    = (const float*)d_in[3];
    const float* Wc    = (const float*)d_in[4];
    const float* gn1_w = (const float*)d_in[5];
    const float* gn1_b = (const float*)d_in[6];
    const float* gn1_a = (const float*)d_in[7];
    const float* gn2_w = (const float*)d_in[8];
    const float* gn2_b = (const float*)d_in[9];
    const float* gn2_a = (const float*)d_in[10];
    const int* src     = (const int*)d_in[11];
    const int* dst     = (const int*)d_in[12];

    char* ws = (char*)d_ws;
    int*   coarse     = (int*)(ws + 0);             // 1 KB   [memset]
    float* stats1     = (float*)(ws + 1024);        // 512 B  [memset]
    float* stats2     = (float*)(ws + 1536);        // 512 B  [memset]
    float* pooledSum  = (float*)(ws + 2048);        // 8 KB   [memset]
    float* ab1        = (float*)(ws + 10240);       // 512 B
    int*   bucketBase = (int*)(ws + 11264);         // 257 ints
    int*   cursor     = (int*)(ws + 12544);         // 1 KB
    int*   rowp       = (int*)(ws + 16384);         // 65537 ints (~256 KB)
    float* inv_so     = (float*)(ws + 294912);      // 256 KB
    float* inv_si     = (float*)(ws + 557056);      // 256 KB
    unsigned int* partial = (unsigned int*)(ws + (1u << 20)); // 4 MB (dead after reduce_src)
    int2*  csr        = (int2*)(ws + (1u << 20));   // 8 MB (overlaps partial)
    int2*  bedges     = (int2*)(ws + (9u << 20));   // 8 MB
    ushort_t* Tbf     = (ushort_t*)(ws + (17u << 20)); // 8 MB bf16 gemm output
    float* bufY       = (float*)(ws + (25u << 20)); // 16 MB fp32 agg output
    float* statsP     = (float*)(ws + (41u << 20)); // 1 MB (2048 x 128)

    hipMemsetAsync(ws, 0, 10240, stream);

    // graph structure (recomputed each call)
    coarse_hist<<<64, 256, 0, stream>>>((const int4*)dst, coarse);
    src_hist<<<64, 256, 0, stream>>>((const int4*)src, partial);
    scan_coarse<<<1, 256, 0, stream>>>(coarse, bucketBase, cursor);
    reduce_src<<<64, 256, 0, stream>>>(partial, (float4*)inv_so);
    bucket_scatter<<<256, 256, 0, stream>>>((const int4*)src, (const int4*)dst,
                                            (const float4*)ew, cursor, bedges);
    refine_kernel<<<NBUCKET, 256, 0, stream>>>(bedges, bucketBase, rowp, inv_si, csr);

    // layer 1
    gemm_kernel<<<N_NODES / 16, 256, 0, stream>>>(x, W1, inv_so, nullptr, nullptr, Tbf);
    agg_kernel<<<N_NODES / 32, 256, 0, stream>>>(Tbf, rowp, inv_si, csr,
                                                 (float4*)bufY, (float4*)statsP, nullptr);
    reduce_stats<<<64, 256, 0, stream>>>(statsP, stats1);
    finalize_kernel<<<1, 64, 0, stream>>>(stats1, stats1 + 64, gn1_w, gn1_b, gn1_a,
                                          ab1 + 0, ab1 + 64);

    // layer 2 (GraphNorm-1 affine fused into GEMM2 load; stats+pool fused into agg)
    gemm_kernel<<<N_NODES / 16, 256, 0, stream>>>(bufY, W2, inv_so, ab1 + 0, ab1 + 64, Tbf);
    agg_kernel<<<N_NODES / 32, 256, 0, stream>>>(Tbf, rowp, inv_si, csr,
                                                 (float4*)bufY, (float4*)statsP, pooledSum);
    reduce_stats<<<64, 256, 0, stream>>>(statsP, stats2);

    // GN2 finalize + pooled affine + classifier (single block)
    out_kernel<<<1, 256, 0, stream>>>(stats2, gn2_w, gn2_b, gn2_a, pooledSum, Wc,
                                      (float*)d_out);
}